// Round 1
// baseline (1289.165 us; speedup 1.0000x reference)
//
#include <hip/hip_runtime.h>
#include <math.h>

// Problem constants
#define N_B 32
#define L_S 4096
#define D_M 768
#define H_N 12
#define DHD 64
#define MLPD 3072

// ws layout (float offsets)
#define WS_QK    0                         // [12][768]  (h-major)
#define WS_QB    9216                      // [12] (pad to 64)
#define WS_ATTN  9280                      // [32*12][4096]
#define WS_XBAR  (9280 + 32*12*4096)       // [32*12][768]
#define WS_XA    (WS_XBAR + 32*12*768)     // [32][768]
#define WS_Y     (WS_XA + 32*768)          // [32][768]
#define WS_H1    (WS_Y + 32*768)           // [32][3072]

// ---------------------------------------------------------------------------
// Kernel A: fold probe through wq (+bq, *1/8) and then through wk -> qk[h][d],
// plus qb[h] = q . bk. One block, trivial cost.
__global__ __launch_bounds__(256) void fold_q_kernel(
    const float* __restrict__ probe, const float* __restrict__ wq,
    const float* __restrict__ bq, const float* __restrict__ wk,
    const float* __restrict__ bk, float* __restrict__ ws) {
    __shared__ float qh_s[768];
    int tid = threadIdx.x;
    for (int i = tid; i < 768; i += 256) {
        float acc = bq[i];
        for (int d = 0; d < 768; ++d) acc += probe[d] * wq[d * 768 + i];
        qh_s[i] = acc * 0.125f;  // 1/sqrt(64)
    }
    __syncthreads();
    float* qk = ws + WS_QK;
    float* qb = ws + WS_QB;
    for (int idx = tid; idx < 9216; idx += 256) {
        int h = idx / 768;
        int d = idx - h * 768;
        const float* wkp = wk + (size_t)d * 768 + h * 64;
        const float* qhp = qh_s + h * 64;
        float acc = 0.f;
        #pragma unroll
        for (int e = 0; e < 64; ++e) acc += qhp[e] * wkp[e];
        qk[idx] = acc;  // qk[h][d]
    }
    if (tid < 12) {
        float acc = 0.f;
        #pragma unroll
        for (int e = 0; e < 64; ++e) acc += qh_s[tid * 64 + e] * bk[tid * 64 + e];
        qb[tid] = acc;
    }
}

// ---------------------------------------------------------------------------
// Kernel 1: logits[n,h,l] = x[n,l,:] . qk[h,:] + qb[h].
// One wave per (n,l) row; lane owns d = lane + 64j (j=0..11).
// qk staged h-major in LDS: lane-consecutive d -> 2-way bank alias (free).
__global__ __launch_bounds__(256) void logits_kernel(
    const float* __restrict__ x, const float* __restrict__ ws_qk,
    const float* __restrict__ ws_qb, float* __restrict__ attn) {
    __shared__ float qk_s[12 * 768];
    __shared__ float qb_s[12];
    int tid = threadIdx.x;
    for (int i = tid; i < 9216; i += 256) qk_s[i] = ws_qk[i];
    if (tid < 12) qb_s[tid] = ws_qb[tid];
    __syncthreads();
    int wave = tid >> 6, lane = tid & 63;
    int row0 = blockIdx.x * 64 + wave * 16;
    for (int rr = 0; rr < 16; ++rr) {
        int row = row0 + rr;
        const float* xr = x + (size_t)row * 768;
        float xv[12];
        #pragma unroll
        for (int j = 0; j < 12; ++j) xv[j] = xr[lane + 64 * j];
        float p[12];
        #pragma unroll
        for (int h = 0; h < 12; ++h) p[h] = 0.f;
        #pragma unroll
        for (int j = 0; j < 12; ++j) {
            float v = xv[j];
            #pragma unroll
            for (int h = 0; h < 12; ++h) p[h] += v * qk_s[h * 768 + lane + 64 * j];
        }
        #pragma unroll
        for (int h = 0; h < 12; ++h) {
            #pragma unroll
            for (int off = 32; off > 0; off >>= 1) p[h] += __shfl_xor(p[h], off);
        }
        if (lane == 0) {
            int n = row >> 12, l = row & 4095;
            #pragma unroll
            for (int h = 0; h < 12; ++h)
                attn[((size_t)(n * 12 + h)) * 4096 + l] = p[h] + qb_s[h];
        }
    }
}

// ---------------------------------------------------------------------------
// Kernel 2: softmax over L=4096, in place. One block per (n,h).
__global__ __launch_bounds__(256) void softmax_kernel(float* __restrict__ attn) {
    float* p = attn + (size_t)blockIdx.x * 4096;
    int tid = threadIdx.x;
    __shared__ float red[4];
    float v[16];
    #pragma unroll
    for (int k = 0; k < 16; ++k) v[k] = p[tid + 256 * k];
    float m = -1e30f;
    #pragma unroll
    for (int k = 0; k < 16; ++k) m = fmaxf(m, v[k]);
    #pragma unroll
    for (int off = 32; off > 0; off >>= 1) m = fmaxf(m, __shfl_xor(m, off));
    int wave = tid >> 6;
    if ((tid & 63) == 0) red[wave] = m;
    __syncthreads();
    m = fmaxf(fmaxf(red[0], red[1]), fmaxf(red[2], red[3]));
    float s = 0.f;
    #pragma unroll
    for (int k = 0; k < 16; ++k) { v[k] = expf(v[k] - m); s += v[k]; }
    #pragma unroll
    for (int off = 32; off > 0; off >>= 1) s += __shfl_xor(s, off);
    __syncthreads();
    if ((tid & 63) == 0) red[wave] = s;
    __syncthreads();
    s = red[0] + red[1] + red[2] + red[3];
    float inv = 1.f / s;
    #pragma unroll
    for (int k = 0; k < 16; ++k) p[tid + 256 * k] = v[k] * inv;
}

// ---------------------------------------------------------------------------
// Kernel 3: xbar[n,h,d] = sum_l attn[n,h,l] * x[n,l,d].
// Grid (lchunk=8, dtile=3, n=32); thread owns one d; attn tile broadcast
// from LDS; partials merged via device atomics (xbar pre-zeroed).
__global__ __launch_bounds__(256) void xbar_kernel(
    const float* __restrict__ x, const float* __restrict__ attn,
    float* __restrict__ xbar) {
    int lchunk = blockIdx.x, dtile = blockIdx.y, n = blockIdx.z;
    __shared__ float at_s[12 * 512];
    int tid = threadIdx.x;
    for (int i = tid; i < 12 * 512; i += 256) {
        int h = i >> 9, l = i & 511;
        at_s[i] = attn[((size_t)(n * 12 + h)) * 4096 + lchunk * 512 + l];
    }
    __syncthreads();
    int d = dtile * 256 + tid;
    float acc[12];
    #pragma unroll
    for (int h = 0; h < 12; ++h) acc[h] = 0.f;
    const float* xp = x + ((size_t)n * 4096 + lchunk * 512) * 768 + d;
    for (int l = 0; l < 512; ++l) {
        float xv = xp[(size_t)l * 768];
        #pragma unroll
        for (int h = 0; h < 12; ++h) acc[h] += at_s[h * 512 + l] * xv;
    }
    #pragma unroll
    for (int h = 0; h < 12; ++h)
        atomicAdd(&xbar[((size_t)(n * 12 + h)) * 768 + d], acc[h]);
}

// ---------------------------------------------------------------------------
// Kernel 4: o = xbar @ wv + bv ; xa = o @ wo + bo ; y = LN(xa). Block per n.
__global__ __launch_bounds__(256) void head_ln_kernel(
    const float* __restrict__ xbar, const float* __restrict__ wv,
    const float* __restrict__ bv, const float* __restrict__ wo,
    const float* __restrict__ bo, const float* __restrict__ ln_scale,
    const float* __restrict__ ln_bias, float* __restrict__ xa_out,
    float* __restrict__ y_out) {
    int n = blockIdx.x, tid = threadIdx.x;
    __shared__ float xb_s[9216];
    __shared__ float o_s[768];
    __shared__ float xa_s[768];
    __shared__ float red[4];
    for (int i = tid; i < 9216; i += 256) xb_s[i] = xbar[(size_t)n * 9216 + i];
    __syncthreads();
    for (int i = tid; i < 768; i += 256) {  // i = h*64+e
        int h = i >> 6;
        float acc = bv[i];
        const float* xbp = xb_s + h * 768;
        for (int d = 0; d < 768; ++d) acc += xbp[d] * wv[(size_t)d * 768 + i];
        o_s[i] = acc;
    }
    __syncthreads();
    for (int i = tid; i < 768; i += 256) {
        float acc = bo[i];
        for (int k = 0; k < 768; ++k) acc += o_s[k] * wo[(size_t)k * 768 + i];
        xa_s[i] = acc;
        xa_out[(size_t)n * 768 + i] = acc;
    }
    __syncthreads();
    float lsum = 0.f;
    for (int i = tid; i < 768; i += 256) lsum += xa_s[i];
    #pragma unroll
    for (int off = 32; off > 0; off >>= 1) lsum += __shfl_xor(lsum, off);
    int wave = tid >> 6;
    if ((tid & 63) == 0) red[wave] = lsum;
    __syncthreads();
    float mu = (red[0] + red[1] + red[2] + red[3]) * (1.f / 768.f);
    __syncthreads();
    float lsq = 0.f;
    for (int i = tid; i < 768; i += 256) { float c = xa_s[i] - mu; lsq += c * c; }
    #pragma unroll
    for (int off = 32; off > 0; off >>= 1) lsq += __shfl_xor(lsq, off);
    if ((tid & 63) == 0) red[wave] = lsq;
    __syncthreads();
    float var = (red[0] + red[1] + red[2] + red[3]) * (1.f / 768.f);
    float rs = rsqrtf(var + 1e-6f);
    for (int i = tid; i < 768; i += 256)
        y_out[(size_t)n * 768 + i] = (xa_s[i] - mu) * rs * ln_scale[i] + ln_bias[i];
}

// ---------------------------------------------------------------------------
// Kernel 5a: h1 = gelu_tanh(y @ w1 + b1). Grid (jtile=12, ngroup=4 of 8 rows).
// w1 column slice read once per jtile; y rows broadcast from LDS.
__global__ __launch_bounds__(256) void mlp1_kernel(
    const float* __restrict__ y, const float* __restrict__ w1,
    const float* __restrict__ b1, float* __restrict__ h1) {
    int jt = blockIdx.x, ng = blockIdx.y;
    int tid = threadIdx.x;
    __shared__ float y_s[8 * 768];
    for (int i = tid; i < 8 * 768; i += 256) y_s[i] = y[(size_t)ng * 8 * 768 + i];
    __syncthreads();
    int j = jt * 256 + tid;
    float acc[8];
    #pragma unroll
    for (int nn = 0; nn < 8; ++nn) acc[nn] = 0.f;
    for (int d = 0; d < 768; ++d) {
        float w = w1[(size_t)d * 3072 + j];
        #pragma unroll
        for (int nn = 0; nn < 8; ++nn) acc[nn] += y_s[nn * 768 + d] * w;
    }
    float bb = b1[j];
    #pragma unroll
    for (int nn = 0; nn < 8; ++nn) {
        float t = acc[nn] + bb;
        float g = 0.5f * t * (1.f + tanhf(0.7978845608028654f * (t + 0.044715f * t * t * t)));
        h1[(size_t)(ng * 8 + nn) * 3072 + j] = g;
    }
}

// ---------------------------------------------------------------------------
// Kernel 5b: out = xa + b2 + h1 @ w2. Grid (dtile=3, n=32).
__global__ __launch_bounds__(256) void mlp2_kernel(
    const float* __restrict__ h1, const float* __restrict__ w2,
    const float* __restrict__ b2, const float* __restrict__ xa,
    float* __restrict__ out) {
    int dt = blockIdx.x, n = blockIdx.y;
    int tid = threadIdx.x;
    __shared__ float h_s[3072];
    for (int i = tid; i < 3072; i += 256) h_s[i] = h1[(size_t)n * 3072 + i];
    __syncthreads();
    int d = dt * 256 + tid;
    float acc = 0.f;
    for (int j = 0; j < 3072; ++j) acc += h_s[j] * w2[(size_t)j * 768 + d];
    out[(size_t)n * 768 + d] = xa[(size_t)n * 768 + d] + b2[d] + acc;
}

// ---------------------------------------------------------------------------
extern "C" void kernel_launch(void* const* d_in, const int* in_sizes, int n_in,
                              void* d_out, int out_size, void* d_ws, size_t ws_size,
                              hipStream_t stream) {
    const float* x        = (const float*)d_in[0];
    const float* probe    = (const float*)d_in[1];
    const float* wq       = (const float*)d_in[2];
    const float* bq       = (const float*)d_in[3];
    const float* wk       = (const float*)d_in[4];
    const float* bk       = (const float*)d_in[5];
    const float* wv       = (const float*)d_in[6];
    const float* bv       = (const float*)d_in[7];
    const float* wo       = (const float*)d_in[8];
    const float* bo       = (const float*)d_in[9];
    const float* ln_scale = (const float*)d_in[10];
    const float* ln_bias  = (const float*)d_in[11];
    const float* w1       = (const float*)d_in[12];
    const float* b1       = (const float*)d_in[13];
    const float* w2       = (const float*)d_in[14];
    const float* b2       = (const float*)d_in[15];
    float* out = (float*)d_out;
    float* ws  = (float*)d_ws;

    float* qk   = ws + WS_QK;
    float* qb   = ws + WS_QB;
    float* attn = ws + WS_ATTN;
    float* xbar = ws + WS_XBAR;
    float* xa   = ws + WS_XA;
    float* y    = ws + WS_Y;
    float* h1   = ws + WS_H1;

    hipMemsetAsync(xbar, 0, (size_t)N_B * H_N * D_M * sizeof(float), stream);
    fold_q_kernel<<<1, 256, 0, stream>>>(probe, wq, bq, wk, bk, ws);
    logits_kernel<<<(N_B * L_S) / 64, 256, 0, stream>>>(x, qk, qb, attn);
    softmax_kernel<<<N_B * H_N, 256, 0, stream>>>(attn);
    xbar_kernel<<<dim3(8, 3, 32), 256, 0, stream>>>(x, attn, xbar);
    head_ln_kernel<<<N_B, 256, 0, stream>>>(xbar, wv, bv, wo, bo, ln_scale,
                                            ln_bias, xa, y);
    mlp1_kernel<<<dim3(12, 4), 256, 0, stream>>>(y, w1, b1, h1);
    mlp2_kernel<<<dim3(3, 32), 256, 0, stream>>>(h1, w2, b2, xa, out);
}

// Round 2
// 820.535 us; speedup vs baseline: 1.5711x; 1.5711x over previous
//
#include <hip/hip_runtime.h>
#include <math.h>

// Problem constants
#define N_B 32
#define L_S 4096
#define D_M 768
#define H_N 12

// ws layout (float offsets). [0, ZERO_N) is zeroed by one memset per call.
#define ZO_QH    0          // 768 (+pad)
#define ZO_XBAR  1024       // [32*12][768]
#define ZO_O     295936     // [32][768]
#define ZO_XA    320512     // [32][768]
#define ZO_H1P   345088     // [32][3072]
#define ZO_MACC  443392     // [32][768]
#define ZERO_N   467968
#define NZ_QK    467968     // [12][768] h-major
#define NZ_QB    477184     // [12] (pad 64)
#define NZ_ATTN  477248     // [32*12][4096]
#define NZ_Y     2050112    // [32][768]
#define NZ_H1    2074688    // [32][3072]

// ---------------------------------------------------------------------------
// qh[i] = 0.125*(probe @ wq + bq)[i]. Split-k: grid (3 itile, 16 ksplit).
__global__ __launch_bounds__(256) void qh_kernel(
    const float* __restrict__ probe, const float* __restrict__ wq,
    const float* __restrict__ bq, float* __restrict__ qh) {
    int i = blockIdx.x * 256 + threadIdx.x;
    int d0 = blockIdx.y * 48;
    float acc = 0.f;
    for (int dd = 0; dd < 48; ++dd)
        acc += probe[d0 + dd] * wq[(size_t)(d0 + dd) * 768 + i];
    acc *= 0.125f;
    if (blockIdx.y == 0) acc += 0.125f * bq[i];
    atomicAdd(&qh[i], acc);
}

// qk[h][d] = sum_e qh[h*64+e]*wk[d*768+h*64+e]; qb[h] = qh_h . bk_h.
__global__ __launch_bounds__(256) void qk_kernel(
    const float* __restrict__ qh, const float* __restrict__ wk,
    const float* __restrict__ bk, float* __restrict__ qk,
    float* __restrict__ qb) {
    int h = blockIdx.x, dt = blockIdx.y, t = threadIdx.x;
    int d = dt * 256 + t;
    const float4* wk4 = (const float4*)(wk + (size_t)d * 768 + h * 64);
    const float4* qh4 = (const float4*)(qh + h * 64);
    float acc = 0.f;
    #pragma unroll
    for (int e4 = 0; e4 < 16; ++e4) {
        float4 w = wk4[e4], q = qh4[e4];
        acc += w.x * q.x + w.y * q.y + w.z * q.z + w.w * q.w;
    }
    qk[h * 768 + d] = acc;
    if (dt == 0 && t < 64) {
        float v = qh[h * 64 + t] * bk[h * 64 + t];
        #pragma unroll
        for (int off = 32; off > 0; off >>= 1) v += __shfl_xor(v, off);
        if (t == 0) qb[h] = v;
    }
}

// ---------------------------------------------------------------------------
// logits: thread-per-row. Thread streams its row (float4, L1-tiled across the
// wave's 64 rows), qk via wave-uniform loads (L1-hot), no LDS, no shuffles.
__global__ __launch_bounds__(256) void logits_kernel(
    const float* __restrict__ x, const float* __restrict__ qk,
    const float* __restrict__ qb, float* __restrict__ attn) {
    int r = blockIdx.x * 256 + threadIdx.x;  // 0..131071
    int n = r >> 12, l = r & 4095;
    const float4* xr4 = (const float4*)(x + (size_t)r * 768);
    const float4* qk4 = (const float4*)qk;
    float p[12];
    #pragma unroll
    for (int h = 0; h < 12; ++h) p[h] = qb[h];
    for (int d4 = 0; d4 < 192; ++d4) {
        float4 xv = xr4[d4];
        #pragma unroll
        for (int h = 0; h < 12; ++h) {
            float4 qv = qk4[h * 192 + d4];
            p[h] += xv.x * qv.x + xv.y * qv.y + xv.z * qv.z + xv.w * qv.w;
        }
    }
    #pragma unroll
    for (int h = 0; h < 12; ++h)
        attn[((size_t)(n * 12 + h)) * 4096 + l] = p[h];
}

// ---------------------------------------------------------------------------
// softmax over L=4096, in place. One block per (n,h).
__global__ __launch_bounds__(256) void softmax_kernel(float* __restrict__ attn) {
    float* p = attn + (size_t)blockIdx.x * 4096;
    int tid = threadIdx.x;
    __shared__ float red[4];
    float v[16];
    #pragma unroll
    for (int k = 0; k < 16; ++k) v[k] = p[tid + 256 * k];
    float m = -1e30f;
    #pragma unroll
    for (int k = 0; k < 16; ++k) m = fmaxf(m, v[k]);
    #pragma unroll
    for (int off = 32; off > 0; off >>= 1) m = fmaxf(m, __shfl_xor(m, off));
    int wave = tid >> 6;
    if ((tid & 63) == 0) red[wave] = m;
    __syncthreads();
    m = fmaxf(fmaxf(red[0], red[1]), fmaxf(red[2], red[3]));
    float s = 0.f;
    #pragma unroll
    for (int k = 0; k < 16; ++k) { v[k] = expf(v[k] - m); s += v[k]; }
    #pragma unroll
    for (int off = 32; off > 0; off >>= 1) s += __shfl_xor(s, off);
    __syncthreads();
    if ((tid & 63) == 0) red[wave] = s;
    __syncthreads();
    s = red[0] + red[1] + red[2] + red[3];
    float inv = 1.f / s;
    #pragma unroll
    for (int k = 0; k < 16; ++k) p[tid + 256 * k] = v[k] * inv;
}

// ---------------------------------------------------------------------------
// xbar[n,h,d] = sum_l attn[n,h,l]*x[n,l,d]. Grid (8 lchunk, 3 dtile, 32 n).
// float4 x loads (48 FMA / 16B); wave w handles h in {3w..3w+2}; attn staged
// transposed [l][16] so per-l weights are 3 consecutive floats (1-2 LDS ops).
__global__ __launch_bounds__(256) void xbar_kernel(
    const float* __restrict__ x, const float* __restrict__ attn,
    float* __restrict__ xbar) {
    int lc = blockIdx.x, dt = blockIdx.y, n = blockIdx.z;
    __shared__ __align__(16) float at_s[512 * 16];
    int t = threadIdx.x;
    for (int i = t; i < 512 * 12; i += 256) {
        int h = i >> 9, l = i & 511;
        at_s[l * 16 + h] = attn[((size_t)(n * 12 + h)) * 4096 + lc * 512 + l];
    }
    __syncthreads();
    int lane = t & 63, w = t >> 6;
    int h0 = w * 3;
    const float4* x4 = (const float4*)x;
    size_t base = ((size_t)n * 4096 + lc * 512) * 192 + dt * 64 + lane;
    float4 a0 = {0, 0, 0, 0}, a1 = {0, 0, 0, 0}, a2 = {0, 0, 0, 0};
    for (int l = 0; l < 512; ++l) {
        float4 xv = x4[base + (size_t)l * 192];
        float w0 = at_s[l * 16 + h0];
        float w1 = at_s[l * 16 + h0 + 1];
        float w2 = at_s[l * 16 + h0 + 2];
        a0.x += w0 * xv.x; a0.y += w0 * xv.y; a0.z += w0 * xv.z; a0.w += w0 * xv.w;
        a1.x += w1 * xv.x; a1.y += w1 * xv.y; a1.z += w1 * xv.z; a1.w += w1 * xv.w;
        a2.x += w2 * xv.x; a2.y += w2 * xv.y; a2.z += w2 * xv.z; a2.w += w2 * xv.w;
    }
    int d = dt * 256 + lane * 4;
    float* b0 = xbar + ((size_t)(n * 12 + h0)) * 768 + d;
    float* b1 = xbar + ((size_t)(n * 12 + h0 + 1)) * 768 + d;
    float* b2 = xbar + ((size_t)(n * 12 + h0 + 2)) * 768 + d;
    atomicAdd(b0 + 0, a0.x); atomicAdd(b0 + 1, a0.y); atomicAdd(b0 + 2, a0.z); atomicAdd(b0 + 3, a0.w);
    atomicAdd(b1 + 0, a1.x); atomicAdd(b1 + 1, a1.y); atomicAdd(b1 + 2, a1.z); atomicAdd(b1 + 3, a1.w);
    atomicAdd(b2 + 0, a2.x); atomicAdd(b2 + 1, a2.y); atomicAdd(b2 + 2, a2.z); atomicAdd(b2 + 3, a2.w);
}

// ---------------------------------------------------------------------------
// o[n][h*64+e] = sum_d xbar[n,h,d]*wv[d,h,e] (+bv at k0). Grid (12 h, 8 k).
__global__ __launch_bounds__(256) void oproj_kernel(
    const float* __restrict__ xbar, const float* __restrict__ wv,
    const float* __restrict__ bv, float* __restrict__ o) {
    int h = blockIdx.x, kk = blockIdx.y, t = threadIdx.x;
    int d0 = kk * 96;
    __shared__ __align__(16) float wv_s[96 * 64];
    __shared__ __align__(16) float xb_s[96 * 32];
    for (int i = t; i < 96 * 64; i += 256) {
        int d = i >> 6, e = i & 63;
        wv_s[i] = wv[(size_t)(d0 + d) * 768 + h * 64 + e];
    }
    for (int i = t; i < 96 * 32; i += 256) {
        int d = i >> 5, nn = i & 31;
        xb_s[i] = xbar[((size_t)(nn * 12 + h)) * 768 + d0 + d];
    }
    __syncthreads();
    int e = t & 63, ng = t >> 6;
    float acc[8] = {0, 0, 0, 0, 0, 0, 0, 0};
    for (int d = 0; d < 96; ++d) {
        float wvv = wv_s[d * 64 + e];
        const float4* xb4 = (const float4*)&xb_s[d * 32 + ng * 8];
        float4 p0 = xb4[0], p1 = xb4[1];
        acc[0] += p0.x * wvv; acc[1] += p0.y * wvv; acc[2] += p0.z * wvv; acc[3] += p0.w * wvv;
        acc[4] += p1.x * wvv; acc[5] += p1.y * wvv; acc[6] += p1.z * wvv; acc[7] += p1.w * wvv;
    }
    float bvv = (kk == 0) ? bv[h * 64 + e] : 0.f;
    #pragma unroll
    for (int k = 0; k < 8; ++k)
        atomicAdd(&o[(size_t)(ng * 8 + k) * 768 + h * 64 + e], acc[k] + bvv);
}

// xa[n][d] = sum_i o[n][i]*wo[i*768+d] (+bo at k0). Grid (3 dtile, 8 k).
__global__ __launch_bounds__(256) void xaproj_kernel(
    const float* __restrict__ o, const float* __restrict__ wo,
    const float* __restrict__ bo, float* __restrict__ xa) {
    int dt = blockIdx.x, kk = blockIdx.y, t = threadIdx.x;
    int i0 = kk * 96;
    __shared__ __align__(16) float o_s[96 * 32];
    for (int idx = t; idx < 96 * 32; idx += 256) {
        int i = idx >> 5, nn = idx & 31;
        o_s[idx] = o[(size_t)nn * 768 + i0 + i];
    }
    __syncthreads();
    int d = dt * 256 + t;
    float acc[32];
    #pragma unroll
    for (int nn = 0; nn < 32; ++nn) acc[nn] = 0.f;
    for (int i = 0; i < 96; ++i) {
        float w = wo[(size_t)(i0 + i) * 768 + d];
        const float4* o4 = (const float4*)&o_s[i * 32];
        #pragma unroll
        for (int q = 0; q < 8; ++q) {
            float4 f = o4[q];
            acc[q * 4 + 0] += f.x * w; acc[q * 4 + 1] += f.y * w;
            acc[q * 4 + 2] += f.z * w; acc[q * 4 + 3] += f.w * w;
        }
    }
    float bov = (kk == 0) ? bo[d] : 0.f;
    #pragma unroll
    for (int nn = 0; nn < 32; ++nn)
        atomicAdd(&xa[(size_t)nn * 768 + d], acc[nn] + bov);
}

// ---------------------------------------------------------------------------
// y = LayerNorm(xa). One block per n.
__global__ __launch_bounds__(256) void ln_kernel(
    const float* __restrict__ xa, const float* __restrict__ ln_scale,
    const float* __restrict__ ln_bias, float* __restrict__ y) {
    int n = blockIdx.x, tid = threadIdx.x;
    __shared__ float xs[768];
    __shared__ float red[4];
    for (int i = tid; i < 768; i += 256) xs[i] = xa[(size_t)n * 768 + i];
    __syncthreads();
    float lsum = 0.f;
    for (int i = tid; i < 768; i += 256) lsum += xs[i];
    #pragma unroll
    for (int off = 32; off > 0; off >>= 1) lsum += __shfl_xor(lsum, off);
    int wave = tid >> 6;
    if ((tid & 63) == 0) red[wave] = lsum;
    __syncthreads();
    float mu = (red[0] + red[1] + red[2] + red[3]) * (1.f / 768.f);
    __syncthreads();
    float lsq = 0.f;
    for (int i = tid; i < 768; i += 256) { float c = xs[i] - mu; lsq += c * c; }
    #pragma unroll
    for (int off = 32; off > 0; off >>= 1) lsq += __shfl_xor(lsq, off);
    if ((tid & 63) == 0) red[wave] = lsq;
    __syncthreads();
    float var = (red[0] + red[1] + red[2] + red[3]) * (1.f / 768.f);
    float rs = rsqrtf(var + 1e-6f);
    for (int i = tid; i < 768; i += 256)
        y[(size_t)n * 768 + i] = (xs[i] - mu) * rs * ln_scale[i] + ln_bias[i];
}

// ---------------------------------------------------------------------------
// h1pre[n][j] += sum_d y[n][d]*w1[d][j]. Grid (12 jtile, 16 k).
__global__ __launch_bounds__(256) void mlp1_kernel(
    const float* __restrict__ y, const float* __restrict__ w1,
    float* __restrict__ h1p) {
    int jt = blockIdx.x, kk = blockIdx.y, t = threadIdx.x;
    int d0 = kk * 48;
    __shared__ __align__(16) float y_s[48 * 32];
    for (int idx = t; idx < 48 * 32; idx += 256) {
        int d = idx >> 5, nn = idx & 31;
        y_s[idx] = y[(size_t)nn * 768 + d0 + d];
    }
    __syncthreads();
    int j = jt * 256 + t;
    float acc[32];
    #pragma unroll
    for (int nn = 0; nn < 32; ++nn) acc[nn] = 0.f;
    for (int d = 0; d < 48; ++d) {
        float w = w1[(size_t)(d0 + d) * 3072 + j];
        const float4* y4 = (const float4*)&y_s[d * 32];
        #pragma unroll
        for (int q = 0; q < 8; ++q) {
            float4 f = y4[q];
            acc[q * 4 + 0] += f.x * w; acc[q * 4 + 1] += f.y * w;
            acc[q * 4 + 2] += f.z * w; acc[q * 4 + 3] += f.w * w;
        }
    }
    #pragma unroll
    for (int nn = 0; nn < 32; ++nn)
        atomicAdd(&h1p[(size_t)nn * 3072 + j], acc[nn]);
}

// h1 = gelu_tanh(h1pre + b1). Grid (12 jtile, 32 n).
__global__ __launch_bounds__(256) void gelu_kernel(
    const float* __restrict__ h1p, const float* __restrict__ b1,
    float* __restrict__ h1) {
    int j = blockIdx.x * 256 + threadIdx.x;
    int n = blockIdx.y;
    float tv = h1p[(size_t)n * 3072 + j] + b1[j];
    float g = 0.5f * tv * (1.f + tanhf(0.7978845608028654f * (tv + 0.044715f * tv * tv * tv)));
    h1[(size_t)n * 3072 + j] = g;
}

// macc[n][d] += sum_j h1[n][j]*w2[j][d]. Grid (3 dtile, 64 k).
__global__ __launch_bounds__(256) void mlp2_kernel(
    const float* __restrict__ h1, const float* __restrict__ w2,
    float* __restrict__ macc) {
    int dt = blockIdx.x, kk = blockIdx.y, t = threadIdx.x;
    int j0 = kk * 48;
    __shared__ __align__(16) float h_s[48 * 32];
    for (int idx = t; idx < 48 * 32; idx += 256) {
        int j = idx >> 5, nn = idx & 31;
        h_s[idx] = h1[(size_t)nn * 3072 + j0 + j];
    }
    __syncthreads();
    int d = dt * 256 + t;
    float acc[32];
    #pragma unroll
    for (int nn = 0; nn < 32; ++nn) acc[nn] = 0.f;
    for (int j = 0; j < 48; ++j) {
        float w = w2[(size_t)(j0 + j) * 768 + d];
        const float4* h4 = (const float4*)&h_s[j * 32];
        #pragma unroll
        for (int q = 0; q < 8; ++q) {
            float4 f = h4[q];
            acc[q * 4 + 0] += f.x * w; acc[q * 4 + 1] += f.y * w;
            acc[q * 4 + 2] += f.z * w; acc[q * 4 + 3] += f.w * w;
        }
    }
    #pragma unroll
    for (int nn = 0; nn < 32; ++nn)
        atomicAdd(&macc[(size_t)nn * 768 + d], acc[nn]);
}

// out = xa + b2 + macc. Grid 32 n.
__global__ __launch_bounds__(256) void final_kernel(
    const float* __restrict__ xa, const float* __restrict__ b2,
    const float* __restrict__ macc, float* __restrict__ out) {
    int n = blockIdx.x, t = threadIdx.x;
    for (int i = t; i < 768; i += 256)
        out[(size_t)n * 768 + i] = xa[(size_t)n * 768 + i] + b2[i] + macc[(size_t)n * 768 + i];
}

// ---------------------------------------------------------------------------
extern "C" void kernel_launch(void* const* d_in, const int* in_sizes, int n_in,
                              void* d_out, int out_size, void* d_ws, size_t ws_size,
                              hipStream_t stream) {
    const float* x        = (const float*)d_in[0];
    const float* probe    = (const float*)d_in[1];
    const float* wq       = (const float*)d_in[2];
    const float* bq       = (const float*)d_in[3];
    const float* wk       = (const float*)d_in[4];
    const float* bk       = (const float*)d_in[5];
    const float* wv       = (const float*)d_in[6];
    const float* bv       = (const float*)d_in[7];
    const float* wo       = (const float*)d_in[8];
    const float* bo       = (const float*)d_in[9];
    const float* ln_scale = (const float*)d_in[10];
    const float* ln_bias  = (const float*)d_in[11];
    const float* w1       = (const float*)d_in[12];
    const float* b1       = (const float*)d_in[13];
    const float* w2       = (const float*)d_in[14];
    const float* b2       = (const float*)d_in[15];
    float* out = (float*)d_out;
    float* ws  = (float*)d_ws;

    float* qh   = ws + ZO_QH;
    float* xbar = ws + ZO_XBAR;
    float* o    = ws + ZO_O;
    float* xa   = ws + ZO_XA;
    float* h1p  = ws + ZO_H1P;
    float* macc = ws + ZO_MACC;
    float* qk   = ws + NZ_QK;
    float* qb   = ws + NZ_QB;
    float* attn = ws + NZ_ATTN;
    float* y    = ws + NZ_Y;
    float* h1   = ws + NZ_H1;

    hipMemsetAsync(ws, 0, (size_t)ZERO_N * sizeof(float), stream);
    qh_kernel<<<dim3(3, 16), 256, 0, stream>>>(probe, wq, bq, qh);
    qk_kernel<<<dim3(12, 3), 256, 0, stream>>>(qh, wk, bk, qk, qb);
    logits_kernel<<<512, 256, 0, stream>>>(x, qk, qb, attn);
    softmax_kernel<<<N_B * H_N, 256, 0, stream>>>(attn);
    xbar_kernel<<<dim3(8, 3, 32), 256, 0, stream>>>(x, attn, xbar);
    oproj_kernel<<<dim3(12, 8), 256, 0, stream>>>(xbar, wv, bv, o);
    xaproj_kernel<<<dim3(3, 8), 256, 0, stream>>>(o, wo, bo, xa);
    ln_kernel<<<N_B, 256, 0, stream>>>(xa, ln_scale, ln_bias, y);
    mlp1_kernel<<<dim3(12, 16), 256, 0, stream>>>(y, w1, h1p);
    gelu_kernel<<<dim3(12, 32), 256, 0, stream>>>(h1p, b1, h1);
    mlp2_kernel<<<dim3(3, 64), 256, 0, stream>>>(h1, w2, macc);
    final_kernel<<<N_B, 256, 0, stream>>>(xa, b2, macc, out);
}